// Round 5
// baseline (3854.116 us; speedup 1.0000x reference)
//
#include <hip/hip_runtime.h>
#include <cstdint>

#define NB 32          // batch
#define TD 32          // decode steps
#define TK 400         // encoder positions
#define HH 512         // hidden
#define H2 1024        // 2H
#define VOCAB 50000
#define OOV 50
#define VEXT (VOCAB + OOV)

// d_out float offsets
#define OUT_OUTPUTS 0LL
#define OUT_H    51251200LL
#define OUT_C    51267584LL
#define OUT_ATTN 51283968LL
#define OUT_PGEN 51693568LL
#define OUT_COV  51694592LL

typedef __attribute__((ext_vector_type(8))) short bf16x8;   // 8 bf16 in 4 VGPRs
typedef __attribute__((ext_vector_type(4))) float f32x4;    // MFMA accumulator

__device__ __forceinline__ float fsigmoid(float x){ return 1.0f/(1.0f+__expf(-x)); }
__device__ __forceinline__ float ftanh(float x){
  float ax = fabsf(x);
  if (ax > 12.0f) return copysignf(1.0f, x);
  float e = __expf(2.0f*x);
  return (e - 1.0f) / (e + 1.0f);
}

// ---------------------------------------------------------------- init
__global__ void k_init(const float* __restrict__ cov0, float* __restrict__ cov,
                       float* __restrict__ ctx0){
  int i = blockIdx.x*256 + threadIdx.x;
  if (i < NB*TK) cov[i] = cov0[i];
  if (i < NB*H2) ctx0[i] = 0.0f;
}

// ---------------------------------------------------------------- fp32 -> (hi,lo) bf16 planes
// hi = truncate-to-bf16 (exact top 16 bits), lo = RNE-bf16(x - hi). x ~= hi + lo, rel err ~2^-17.
__global__ __launch_bounds__(256) void k_split(
    const float* __restrict__ in, ushort* __restrict__ hi, ushort* __restrict__ lo, int n4)
{
  int i = blockIdx.x*256 + threadIdx.x;
  if (i >= n4) return;
  float4 f = ((const float4*)in)[i];
  ushort4 h, l;
  {
    uint u = __float_as_uint(f.x); h.x = (ushort)(u>>16);
    uint v = __float_as_uint(f.x - __uint_as_float(u & 0xffff0000u));
    l.x = (ushort)((v + 0x7fffu + ((v>>16)&1u)) >> 16);
  }
  {
    uint u = __float_as_uint(f.y); h.y = (ushort)(u>>16);
    uint v = __float_as_uint(f.y - __uint_as_float(u & 0xffff0000u));
    l.y = (ushort)((v + 0x7fffu + ((v>>16)&1u)) >> 16);
  }
  {
    uint u = __float_as_uint(f.z); h.z = (ushort)(u>>16);
    uint v = __float_as_uint(f.z - __uint_as_float(u & 0xffff0000u));
    l.z = (ushort)((v + 0x7fffu + ((v>>16)&1u)) >> 16);
  }
  {
    uint u = __float_as_uint(f.w); h.w = (ushort)(u>>16);
    uint v = __float_as_uint(f.w - __uint_as_float(u & 0xffff0000u));
    l.w = (ushort)((v + 0x7fffu + ((v>>16)&1u)) >> 16);
  }
  ((ushort4*)hi)[i] = h;
  ((ushort4*)lo)[i] = l;
}

// ---------------------------------------------------------------- MFMA split-bf16 GEMM
// C[M,N] = (Ah+Al)[M,K] @ W[N,K]^T (+bias), via 3 bf16 MFMA products, fp32 accum.
// A: pre-split bf16 planes row-major [M][K]. W: fp32 [Nrows][K], split on the fly in staging.
// 128x128 tile, BK=32, 256 threads = 4 waves (2x2 of 64x64), 16x16x32 MFMA.
// LDS rows padded to 40 bf16 (80B): 16B-aligned b128 reads, 2-way bank aliasing (free).
__global__ __launch_bounds__(256) void mfma_gemm(
    const ushort* __restrict__ Ah, const ushort* __restrict__ Al, int K,
    const float* __restrict__ W, int Nrows, const float* __restrict__ bias,
    float* __restrict__ C, long long ldc, int permute)
{
  __shared__ __align__(16) ushort lAh[128*40];
  __shared__ __align__(16) ushort lAl[128*40];
  __shared__ __align__(16) ushort lBh[128*40];
  __shared__ __align__(16) ushort lBl[128*40];
  const int tid  = threadIdx.x;
  const int n0   = blockIdx.x*128;
  const int m0   = blockIdx.y*128;
  const int wave = tid >> 6, lane = tid & 63;
  const int wr   = wave >> 1, wc = wave & 1;   // 64x64 wave sub-tile
  const int r16  = lane & 15, g = lane >> 4;   // lane row / k-group
  f32x4 acc[4][4] = {};
  for (int kt = 0; kt < K; kt += 32){
    // ---- stage A planes: 1024 x 16B units (u = plane*512 + r*4 + chunk)
#pragma unroll
    for (int i = 0; i < 4; ++i){
      int u = tid + i*256;
      int chunk = u & 3, r = (u >> 2) & 127, pl = u >> 9;
      const ushort* src = (pl ? Al : Ah) + (size_t)(m0 + r)*K + kt + chunk*8;
      bf16x8 v = *(const bf16x8*)src;
      *(bf16x8*)((pl ? lAl : lAh) + r*40 + chunk*8) = v;
    }
    // ---- stage B with on-the-fly split: 1024 float4 units (u = r*8 + chunk)
#pragma unroll
    for (int i = 0; i < 4; ++i){
      int u = tid + i*256;
      int chunk = u & 7, r = (u >> 3) & 127;
      int wrow = n0 + r; if (wrow > Nrows - 1) wrow = Nrows - 1;
      float4 f = *(const float4*)(W + (size_t)wrow*K + kt + chunk*4);
      uint ux = __float_as_uint(f.x), uy = __float_as_uint(f.y);
      uint uz = __float_as_uint(f.z), uw = __float_as_uint(f.w);
      uint h0 = (ux >> 16) | (uy & 0xffff0000u);
      uint h1 = (uz >> 16) | (uw & 0xffff0000u);
      float rx = f.x - __uint_as_float(ux & 0xffff0000u);
      float ry = f.y - __uint_as_float(uy & 0xffff0000u);
      float rz = f.z - __uint_as_float(uz & 0xffff0000u);
      float rw = f.w - __uint_as_float(uw & 0xffff0000u);
      uint l0 = (__float_as_uint(rx) >> 16) | (__float_as_uint(ry) & 0xffff0000u);
      uint l1 = (__float_as_uint(rz) >> 16) | (__float_as_uint(rw) & 0xffff0000u);
      *(uint2*)(lBh + r*40 + chunk*4) = make_uint2(h0, h1);
      *(uint2*)(lBl + r*40 + chunk*4) = make_uint2(l0, l1);
    }
    __syncthreads();
    // ---- fragments (same (g,j)->k map on A and B sides => exact dot product)
    bf16x8 fah[4], fal[4], fbh[4], fbl[4];
#pragma unroll
    for (int mi = 0; mi < 4; ++mi){
      int row = wr*64 + mi*16 + r16;
      fah[mi] = *(const bf16x8*)(lAh + row*40 + g*8);
      fal[mi] = *(const bf16x8*)(lAl + row*40 + g*8);
    }
#pragma unroll
    for (int ni = 0; ni < 4; ++ni){
      int row = wc*64 + ni*16 + r16;
      fbh[ni] = *(const bf16x8*)(lBh + row*40 + g*8);
      fbl[ni] = *(const bf16x8*)(lBl + row*40 + g*8);
    }
#pragma unroll
    for (int mi = 0; mi < 4; ++mi)
#pragma unroll
      for (int ni = 0; ni < 4; ++ni){
        acc[mi][ni] = __builtin_amdgcn_mfma_f32_16x16x32_bf16(fah[mi], fbh[ni], acc[mi][ni], 0, 0, 0);
        acc[mi][ni] = __builtin_amdgcn_mfma_f32_16x16x32_bf16(fah[mi], fbl[ni], acc[mi][ni], 0, 0, 0);
        acc[mi][ni] = __builtin_amdgcn_mfma_f32_16x16x32_bf16(fal[mi], fbh[ni], acc[mi][ni], 0, 0, 0);
      }
    __syncthreads();
  }
  // ---- epilogue. C/D layout (HW-verified): col = lane&15, row = g*4 + reg.
#pragma unroll
  for (int mi = 0; mi < 4; ++mi)
#pragma unroll
    for (int ni = 0; ni < 4; ++ni)
#pragma unroll
      for (int reg = 0; reg < 4; ++reg){
        int m = m0 + wr*64 + mi*16 + g*4 + reg;
        int n = n0 + wc*64 + ni*16 + r16;
        if (n < Nrows){
          float v = acc[mi][ni][reg];
          if (bias) v += bias[n];
          long long ro = permute ? (long long)((m & 31)*32 + (m >> 5)) : (long long)m;
          C[ro*ldc + n] = v;
        }
      }
}

// ---------------------------------------------------------------- fp32 tiled GEMM (kept for W1)
__global__ __launch_bounds__(256) void big_gemm(
    const float* __restrict__ A1, int lda1, int K1,
    const float* __restrict__ A2, int lda2, int K2,
    const float* __restrict__ W, int ldw, int Nrows,
    const float* __restrict__ bias,
    float* __restrict__ C, long long ldc, int permute)
{
  __shared__ float AsT[16][132];
  __shared__ float WsT[16][132];
  const int tid = threadIdx.x;
  const int n0 = blockIdx.x*128;
  const int m0 = blockIdx.y*128;
  const int tx = tid & 15, ty = tid >> 4;
  const int lr = tid >> 2;        // 0..63
  const int lk = (tid & 3) * 4;   // 0,4,8,12
  float acc[8][8] = {};
  const int K = K1 + K2;
  for (int kt = 0; kt < K; kt += 16){
    const bool side1 = (kt < K1);
#pragma unroll
    for (int p = 0; p < 2; ++p){
      int row = lr + p*64;
      const float* src = side1 ? (A1 + (size_t)(m0+row)*lda1 + (kt+lk))
                               : (A2 + (size_t)(m0+row)*lda2 + (kt-K1+lk));
      float4 v = *(const float4*)src;
      AsT[lk+0][row]=v.x; AsT[lk+1][row]=v.y; AsT[lk+2][row]=v.z; AsT[lk+3][row]=v.w;
    }
#pragma unroll
    for (int p = 0; p < 2; ++p){
      int row = lr + p*64;
      int n = n0 + row; if (n > Nrows-1) n = Nrows-1;
      const float* src = W + (size_t)n*ldw + kt + lk;
      float4 v = *(const float4*)src;
      WsT[lk+0][row]=v.x; WsT[lk+1][row]=v.y; WsT[lk+2][row]=v.z; WsT[lk+3][row]=v.w;
    }
    __syncthreads();
#pragma unroll
    for (int kk = 0; kk < 16; ++kk){
      float a[8], w[8];
      *(float4*)&a[0] = *(const float4*)&AsT[kk][ty*8];
      *(float4*)&a[4] = *(const float4*)&AsT[kk][ty*8+4];
      *(float4*)&w[0] = *(const float4*)&WsT[kk][tx*8];
      *(float4*)&w[4] = *(const float4*)&WsT[kk][tx*8+4];
#pragma unroll
      for (int i = 0; i < 8; ++i)
#pragma unroll
        for (int j = 0; j < 8; ++j)
          acc[i][j] += a[i]*w[j];
    }
    __syncthreads();
  }
#pragma unroll
  for (int i = 0; i < 8; ++i){
    int r = m0 + ty*8 + i;
    long long ro = permute ? (long long)((r & 31)*32 + (r >> 5)) : (long long)r;
    float* dst = C + ro*ldc;
#pragma unroll
    for (int j = 0; j < 8; ++j){
      int n = n0 + tx*8 + j;
      if (n < Nrows){
        float v = acc[i][j];
        if (bias) v += bias[n];
        dst[n] = v;
      }
    }
  }
}

// ---------------------------------------------------------------- small GEMM (M=32)
__global__ __launch_bounds__(128) void small_gemm(
    const float* __restrict__ A1, int lda1, int K1, int a1_slabs, int a1_slab_stride,
    float* __restrict__ a1_sum_out,
    const float* __restrict__ A2, int lda2,
    const int* __restrict__ a2_rows, int a2_rows_stride,
    const float* __restrict__ W1, int ldW1,
    const float* __restrict__ W2, int ldW2,
    const float* __restrict__ bias1, const float* __restrict__ bias2,
    float* __restrict__ Cslab, int N, int kchunk)
{
  __shared__ float AsT[32][36];
  __shared__ float WsT[32][132];
  const int tid = threadIdx.x;
  const int n0 = blockIdx.x * 128;
  const int ky = blockIdx.y;
  const int ty = tid >> 5;
  const int tx = tid & 31;
  const int lm = tid >> 2;
  const int lk = (tid & 3) * 8;
  float acc[8][4] = {};
  const int kbeg = ky*kchunk, kend = kbeg + kchunk;
  for (int kt = kbeg; kt < kend; kt += 32){
    const bool side1 = (kt < K1);
    float4 va0, va1;
    if (side1){
      size_t boff = (size_t)lm*lda1 + kt + lk;
      if (a1_slabs > 1){
        va0 = make_float4(0,0,0,0); va1 = make_float4(0,0,0,0);
        for (int s = 0; s < a1_slabs; ++s){
          const float* p = A1 + (size_t)s*a1_slab_stride + boff;
          float4 t0 = *(const float4*)p, t1 = *(const float4*)(p+4);
          va0.x+=t0.x; va0.y+=t0.y; va0.z+=t0.z; va0.w+=t0.w;
          va1.x+=t1.x; va1.y+=t1.y; va1.z+=t1.z; va1.w+=t1.w;
        }
        if (a1_sum_out != nullptr && blockIdx.x == 0){
          *(float4*)(a1_sum_out + boff) = va0;
          *(float4*)(a1_sum_out + boff + 4) = va1;
        }
      } else {
        const float* p = A1 + boff;
        va0 = *(const float4*)p; va1 = *(const float4*)(p+4);
      }
    } else {
      const float* base = a2_rows
        ? (A2 + (size_t)a2_rows[lm*a2_rows_stride]*lda2)
        : (A2 + (size_t)lm*lda2);
      const float* p = base + (kt - K1) + lk;
      va0 = *(const float4*)p; va1 = *(const float4*)(p+4);
    }
    AsT[lk+0][lm]=va0.x; AsT[lk+1][lm]=va0.y; AsT[lk+2][lm]=va0.z; AsT[lk+3][lm]=va0.w;
    AsT[lk+4][lm]=va1.x; AsT[lk+5][lm]=va1.y; AsT[lk+6][lm]=va1.z; AsT[lk+7][lm]=va1.w;
#pragma unroll
    for (int p = 0; p < 4; ++p){
      int col = lm + p*32;
      int n = n0 + col;
      const float* wsrc = side1 ? (W1 + (size_t)n*ldW1 + kt + lk)
                                : (W2 + (size_t)n*ldW2 + (kt-K1) + lk);
      float4 w0 = *(const float4*)wsrc, w1 = *(const float4*)(wsrc+4);
      WsT[lk+0][col]=w0.x; WsT[lk+1][col]=w0.y; WsT[lk+2][col]=w0.z; WsT[lk+3][col]=w0.w;
      WsT[lk+4][col]=w1.x; WsT[lk+5][col]=w1.y; WsT[lk+6][col]=w1.z; WsT[lk+7][col]=w1.w;
    }
    __syncthreads();
#pragma unroll
    for (int kk = 0; kk < 32; ++kk){
      float a[8];
      *(float4*)&a[0] = *(const float4*)&AsT[kk][ty*8];
      *(float4*)&a[4] = *(const float4*)&AsT[kk][ty*8+4];
      float4 w = *(const float4*)&WsT[kk][tx*4];
#pragma unroll
      for (int i = 0; i < 8; ++i){
        acc[i][0] += a[i]*w.x;
        acc[i][1] += a[i]*w.y;
        acc[i][2] += a[i]*w.z;
        acc[i][3] += a[i]*w.w;
      }
    }
    __syncthreads();
  }
  float* out = Cslab + (size_t)ky*32*N;
  const bool addb = (ky == 0) && (bias1 != nullptr);
#pragma unroll
  for (int i = 0; i < 8; ++i){
    int m = ty*8 + i;
    int n = n0 + tx*4;
    float4 v = make_float4(acc[i][0], acc[i][1], acc[i][2], acc[i][3]);
    if (addb){
      v.x += bias1[n+0]; v.y += bias1[n+1]; v.z += bias1[n+2]; v.w += bias1[n+3];
      if (bias2){ v.x += bias2[n+0]; v.y += bias2[n+1]; v.z += bias2[n+2]; v.w += bias2[n+3]; }
    }
    *(float4*)(out + (size_t)m*N + n) = v;
  }
}

// ---------------------------------------------------------------- LSTM pointwise
__global__ __launch_bounds__(256) void k_lstm(
    const float* __restrict__ gslab, const float* __restrict__ c_prev,
    float* __restrict__ h_out, float* __restrict__ c_out)
{
  int i = blockIdx.x*256 + threadIdx.x;
  int b = i >> 9, j = i & 511;
  size_t base = (size_t)b*2048 + j;
  float ig=0.f, fg=0.f, gg=0.f, og=0.f;
#pragma unroll
  for (int s = 0; s < 16; ++s){
    const float* g = gslab + (size_t)s*65536 + base;
    ig += g[0]; fg += g[512]; gg += g[1024]; og += g[1536];
  }
  float c = fsigmoid(fg) * c_prev[i] + fsigmoid(ig) * ftanh(gg);
  h_out[i] = fsigmoid(og) * ftanh(c);
  c_out[i] = c;
}

// ---------------------------------------------------------------- attention scores
__global__ __launch_bounds__(256) void k_scores(
    const float* __restrict__ ef, const float* __restrict__ dslab,
    const float* __restrict__ cov, const float* __restrict__ Wc,
    const float* __restrict__ vw, float* __restrict__ scores)
{
  int wv = threadIdx.x >> 6, lane = threadIdx.x & 63;
  int row = blockIdx.x*4 + wv;           // b*TK + t
  int b = row / TK;
  float cv = cov[row];
  const float4* ef4 = (const float4*)ef + (size_t)row*256;
  const float4* d4  = (const float4*)dslab + (size_t)b*256;
  const float4* wc4 = (const float4*)Wc;
  const float4* v4  = (const float4*)vw;
  float acc = 0.f;
#pragma unroll
  for (int j = 0; j < 4; ++j){
    int idx = j*64 + lane;
    float4 d = d4[idx];
#pragma unroll
    for (int s = 1; s < 8; ++s){
      float4 t = d4[idx + s*8192];
      d.x+=t.x; d.y+=t.y; d.z+=t.z; d.w+=t.w;
    }
    float4 e = ef4[idx], w = wc4[idx], v = v4[idx];
    acc += v.x*ftanh(e.x + d.x + cv*w.x);
    acc += v.y*ftanh(e.y + d.y + cv*w.y);
    acc += v.z*ftanh(e.z + d.z + cv*w.z);
    acc += v.w*ftanh(e.w + d.w + cv*w.w);
  }
  for (int o = 32; o; o >>= 1) acc += __shfl_xor(acc, o);
  if (lane == 0) scores[row] = acc;
}

// ---------------------------------------------------------------- softmax+mask+cov
__global__ __launch_bounds__(256) void k_attn(
    const float* __restrict__ scores, const float* __restrict__ mask,
    float* __restrict__ cov, float* __restrict__ attnb,
    float* __restrict__ attn_out, float* __restrict__ cov_out,
    float* __restrict__ ct_row)
{
  __shared__ float red[256];
  int b = blockIdx.x, tid = threadIdx.x;
  const float* sc = scores + b*TK;
  float m = -1e30f;
  for (int t = tid; t < TK; t += 256) m = fmaxf(m, sc[t]);
  red[tid] = m; __syncthreads();
  for (int s = 128; s; s >>= 1){ if (tid < s) red[tid] = fmaxf(red[tid], red[tid+s]); __syncthreads(); }
  float mx = red[0]; __syncthreads();
  float s0 = 0.f;
  for (int t = tid; t < TK; t += 256) s0 += __expf(sc[t]-mx);
  red[tid] = s0; __syncthreads();
  for (int s = 128; s; s >>= 1){ if (tid < s) red[tid] += red[tid+s]; __syncthreads(); }
  float inv1 = 1.f/red[0]; __syncthreads();
  float s1 = 0.f;
  for (int t = tid; t < TK; t += 256) s1 += __expf(sc[t]-mx)*inv1*mask[b*TK+t];
  red[tid] = s1; __syncthreads();
  for (int s = 128; s; s >>= 1){ if (tid < s) red[tid] += red[tid+s]; __syncthreads(); }
  float inv2 = 1.f/red[0];
  for (int t = tid; t < TK; t += 256){
    float a = __expf(sc[t]-mx)*inv1*mask[b*TK+t]*inv2;
    attnb[b*TK+t] = a;
    attn_out[(size_t)b*TD*TK + t] = a;
    float cn = cov[b*TK+t] + a;
    cov_out[(size_t)b*TD*TK + t] = cn;
    cov[b*TK+t] = cn;
  }
  for (int n = tid; n < H2; n += 256) ct_row[(size_t)b*H2 + n] = 0.f;
}

// ---------------------------------------------------------------- context c_t
__global__ __launch_bounds__(256) void k_ctx(
    const float* __restrict__ attnb, const float* __restrict__ eo,
    float* __restrict__ ct_rows)
{
  int b = blockIdx.x >> 3;
  int chunk = blockIdx.x & 7;
  int tid = threadIdx.x;
  float acc[4] = {0.f,0.f,0.f,0.f};
  int t0 = chunk*50;
  for (int tt = 0; tt < 50; ++tt){
    int row = b*TK + t0 + tt;
    float a = attnb[row];
    const float* er = eo + (size_t)row*H2;
#pragma unroll
    for (int j = 0; j < 4; ++j) acc[j] += a * er[tid + j*256];
  }
#pragma unroll
  for (int j = 0; j < 4; ++j) atomicAdd(&ct_rows[(size_t)b*H2 + tid + j*256], acc[j]);
}

// ---------------------------------------------------------------- p_gen (deferred)
__global__ __launch_bounds__(256) void k_pgen(
    const float* __restrict__ ct_all, const float* __restrict__ h_all,
    const float* __restrict__ c_all, const float* __restrict__ x_all,
    const float* __restrict__ Wpg, const float* __restrict__ bpg,
    float* __restrict__ pgen_all, float* __restrict__ pgen_out)
{
  int wv = threadIdx.x >> 6, lane = threadIdx.x & 63;
  int r = blockIdx.x*4 + wv;             // td*32+b
  float acc = 0.f;
  const float* ct = ct_all + (size_t)r*H2;
  const float* h  = h_all  + (size_t)r*HH;
  const float* c  = c_all  + (size_t)r*HH;
  const float* x  = x_all  + (size_t)r*HH;
  for (int k = lane; k < H2; k += 64) acc += ct[k]*Wpg[k];
  for (int k = lane; k < HH; k += 64)
    acc += h[k]*Wpg[1024+k] + c[k]*Wpg[1536+k] + x[k]*Wpg[2048+k];
  for (int o = 32; o; o >>= 1) acc += __shfl_xor(acc, o);
  if (lane == 0){
    float p = fsigmoid(acc + bpg[0]);
    pgen_all[r] = p;
    int td = r >> 5, b = r & 31;
    pgen_out[b*TD + td] = p;
  }
}

// ---------------------------------------------------------------- vocab softmax + scatter
__global__ __launch_bounds__(256) void k_softmax_scatter(
    float* __restrict__ outbase, const float* __restrict__ pgen_all,
    const float* __restrict__ attn_all, const int* __restrict__ ebev,
    const float* __restrict__ extra_zeros)
{
  __shared__ float red[256];
  int blk = blockIdx.x;          // b*TD + td
  int tid = threadIdx.x;
  int b = blk >> 5, td = blk & 31;
  float* row = outbase + (size_t)blk * VEXT;
  float pg = pgen_all[td*NB + b];
  float m = -1e30f;
  for (int i = tid; i < VOCAB; i += 256) m = fmaxf(m, row[i]);
  red[tid] = m; __syncthreads();
  for (int s = 128; s; s >>= 1){ if (tid < s) red[tid] = fmaxf(red[tid], red[tid+s]); __syncthreads(); }
  float mx = red[0]; __syncthreads();
  float s0 = 0.f;
  for (int i = tid; i < VOCAB; i += 256) s0 += __expf(row[i]-mx);
  red[tid] = s0; __syncthreads();
  for (int s = 128; s; s >>= 1){ if (tid < s) red[tid] += red[tid+s]; __syncthreads(); }
  float scale = pg / red[0];
  for (int i = tid; i < VOCAB; i += 256) row[i] = __expf(row[i]-mx)*scale;
  for (int i = VOCAB+tid; i < VEXT; i += 256) row[i] = extra_zeros[b*OOV + (i-VOCAB)];
  __syncthreads();
  float q = 1.0f - pg;
  const int* ids = ebev + b*TK;
  const float* at = attn_all + (size_t)b*TD*TK + (size_t)td*TK;
  for (int t = tid; t < TK; t += 256) atomicAdd(&row[ids[t]], q*at[t]);
}

// ---------------------------------------------------------------- final h,c
__global__ void k_hc(const float* __restrict__ h_all, const float* __restrict__ c_all,
                     float* __restrict__ oh, float* __restrict__ oc){
  int i = blockIdx.x*256 + threadIdx.x;
  if (i < NB*HH){ oh[i] = h_all[507904 + i]; oc[i] = c_all[507904 + i]; }
}

// ================================================================ host
extern "C" void kernel_launch(void* const* d_in, const int* in_sizes, int n_in,
                              void* d_out_v, int out_size, void* d_ws, size_t ws_size,
                              hipStream_t stream)
{
  (void)in_sizes; (void)n_in; (void)out_size; (void)ws_size;
  const int*   inputs   = (const int*)d_in[0];
  const float* h0       = (const float*)d_in[1];
  const float* c0       = (const float*)d_in[2];
  const float* eo       = (const float*)d_in[3];
  const float* mask     = (const float*)d_in[4];
  const float* extraz   = (const float*)d_in[5];
  const int*   ebev     = (const int*)d_in[6];
  const float* cov0     = (const float*)d_in[7];
  const float* emb      = (const float*)d_in[8];
  const float* W_ih     = (const float*)d_in[9];
  const float* W_hh     = (const float*)d_in[10];
  const float* b_ih     = (const float*)d_in[11];
  const float* b_hh     = (const float*)d_in[12];
  const float* Wx       = (const float*)d_in[13];
  const float* bx       = (const float*)d_in[14];
  const float* Wpg      = (const float*)d_in[15];
  const float* bpg      = (const float*)d_in[16];
  const float* Wenc     = (const float*)d_in[17];
  const float* Wp       = (const float*)d_in[18];
  const float* bp       = (const float*)d_in[19];
  const float* vw       = (const float*)d_in[20];
  const float* Wc       = (const float*)d_in[21];
  const float* W1       = (const float*)d_in[22];
  const float* b1       = (const float*)d_in[23];
  const float* W2       = (const float*)d_in[24];
  const float* b2       = (const float*)d_in[25];
  float* dout = (float*)d_out_v;

  float* ws = (float*)d_ws;
  size_t off = 0;
  auto alloc = [&](size_t n){ float* p = ws + off; off += (n + 255) & ~(size_t)255; return p; };
  float* ctx0   = alloc(32768);
  float* x_part = alloc(16*16384);
  float* x_all  = alloc(1024*512);
  float* g_part = alloc(16*65536);
  float* d_part = alloc(8*32768);
  float* scores = alloc(12800);
  float* attnb  = alloc(12800);
  float* cov    = alloc(12800);
  float* pgen   = alloc(1024);
  float* h_all  = alloc(1024*512);
  float* c_all  = alloc(1024*512);
  float* ct_all = alloc(1024*1024);
  float* out_all= alloc(1024*512);
  ushort* outh  = (ushort*)alloc(131072);   // out_all hi plane (1024x512 bf16)
  ushort* outl  = (ushort*)alloc(131072);   // out_all lo plane

  // d_out region reuse (all dead before the logits GEMM overwrites [0, 51.25M)):
  float* ef = dout;                                  // enc_feature [12800][1024] at slots [0, 13.1M)
  ushort* eoh = (ushort*)(dout + 13107200);          // eo hi plane, slots [13.1M, 19.66M)
  ushort* eol = (ushort*)(dout + 19660800);          // eo lo plane, slots [19.66M, 26.2M)

  hipLaunchKernelGGL(k_init, dim3(128), dim3(256), 0, stream, cov0, cov, ctx0);

  // split eo -> bf16 planes (12800x1024 = 13107200 elems, /4 = 3276800 units)
  hipLaunchKernelGGL(k_split, dim3(12800), dim3(256), 0, stream, eo, eoh, eol, 3276800);

  // enc_feature = eo @ Wenc^T  via split-bf16 MFMA  (M=12800, N=1024, K=1024)
  hipLaunchKernelGGL(mfma_gemm, dim3(8,100), dim3(256), 0, stream,
    eoh, eol, 1024, Wenc, 1024, (const float*)nullptr, ef, (long long)1024, 0);

  for (int td = 0; td < TD; ++td){
    const float* ctxA  = (td == 0) ? ctx0 : (ct_all + (size_t)(td-1)*32768);
    const float* hprev = (td == 0) ? h0   : (h_all  + (size_t)(td-1)*16384);
    const float* cprev = (td == 0) ? c0   : (c_all  + (size_t)(td-1)*16384);

    hipLaunchKernelGGL(small_gemm, dim3(4,16), dim3(128), 0, stream,
      ctxA, 1024, 1024, 1, 0, (float*)nullptr,
      emb, 512, inputs + td, TD,
      Wx, 1536, Wx + 1024, 1536,
      bx, (const float*)nullptr,
      x_part, 512, 96);

    hipLaunchKernelGGL(small_gemm, dim3(16,16), dim3(128), 0, stream,
      x_part, 512, 512, 16, 16384, x_all + (size_t)td*16384,
      hprev, 512, (const int*)nullptr, 0,
      W_ih, 512, W_hh, 512,
      b_ih, b_hh,
      g_part, 2048, 64);

    hipLaunchKernelGGL(k_lstm, dim3(64), dim3(256), 0, stream,
      g_part, cprev, h_all + (size_t)td*16384, c_all + (size_t)td*16384);

    hipLaunchKernelGGL(small_gemm, dim3(8,8), dim3(128), 0, stream,
      h_all + (size_t)td*16384, 512, 512, 1, 0, (float*)nullptr,
      c_all + (size_t)td*16384, 512, (const int*)nullptr, 0,
      Wp, 1024, Wp + 512, 1024,
      bp, (const float*)nullptr,
      d_part, 1024, 128);

    hipLaunchKernelGGL(k_scores, dim3(3200), dim3(256), 0, stream,
      ef, d_part, cov, Wc, vw, scores);

    hipLaunchKernelGGL(k_attn, dim3(32), dim3(256), 0, stream,
      scores, mask, cov, attnb,
      dout + OUT_ATTN + (size_t)td*TK,
      dout + OUT_COV  + (size_t)td*TK,
      ct_all + (size_t)td*32768);

    hipLaunchKernelGGL(k_ctx, dim3(256), dim3(256), 0, stream,
      attnb, eo, ct_all + (size_t)td*32768);
  }

  // out = [h | c_t] @ W1^T + b1 (fp32; small)
  hipLaunchKernelGGL(big_gemm, dim3(4,8), dim3(256), 0, stream,
    h_all, 512, 512, ct_all, 1024, 1024,
    W1, 1536, 512, b1,
    out_all, (long long)512, 0);

  // split out_all -> bf16 planes (524288 elems, /4 = 131072 units)
  hipLaunchKernelGGL(k_split, dim3(512), dim3(256), 0, stream, out_all, outh, outl, 131072);

  hipLaunchKernelGGL(k_pgen, dim3(256), dim3(256), 0, stream,
    ct_all, h_all, c_all, x_all, Wpg, bpg, pgen, dout + OUT_PGEN);

  // logits = out @ W2^T + b2 via split-bf16 MFMA, row-permuted into outputs region
  hipLaunchKernelGGL(mfma_gemm, dim3(391,8), dim3(256), 0, stream,
    outh, outl, 512, W2, VOCAB, b2, dout, (long long)VEXT, 1);

  hipLaunchKernelGGL(k_softmax_scatter, dim3(1024), dim3(256), 0, stream,
    dout, pgen, dout + OUT_ATTN, ebev, extraz);

  hipLaunchKernelGGL(k_hc, dim3(64), dim3(256), 0, stream,
    h_all, c_all, dout + OUT_H, dout + OUT_C);
}